// Round 3
// baseline (2509.579 us; speedup 1.0000x reference)
//
#include <hip/hip_runtime.h>
#include <hip/hip_cooperative_groups.h>

namespace cg = cooperative_groups;

#define D 2048
#define T 1024
#define GI_STRIDE (3 * D)  // gi row: [r | z | n]

__device__ __forceinline__ float sigf(float x) {
    return 1.0f / (1.0f + __expf(-x));
}
__device__ __forceinline__ float tanhfast(float x) {
    float e = __expf(-2.0f * fabsf(x));
    float t = (1.0f - e) / (1.0f + e);
    return copysignf(t, x);
}

// ---------------------------------------------------------------------------
// Kernel A: input projections  gi[t][g][j] = X[t,:] @ W_g + b_g   (g = r,z,n)
// M=1024, N=6144 (3 gates x 2048), K=2048. Tile: 128(t) x 64(j), one gate/block.
// ---------------------------------------------------------------------------
__global__ __launch_bounds__(256) void kA(
    const float* __restrict__ X,
    const float* __restrict__ wir, const float* __restrict__ wiz, const float* __restrict__ win,
    const float* __restrict__ bir, const float* __restrict__ biz, const float* __restrict__ bin,
    float* __restrict__ gi)
{
    __shared__ float Xs[128 * 33];
    __shared__ float Ws[32 * 64];

    const int tid = threadIdx.x;
    const int tx = tid & 15;
    const int ty = tid >> 4;
    const int g  = blockIdx.x >> 5;
    const int jt = blockIdx.x & 31;
    const int j0 = jt * 64;
    const int t0 = blockIdx.y * 128;

    const float* __restrict__ W    = (g == 0) ? wir : (g == 1) ? wiz : win;
    const float* __restrict__ bias = (g == 0) ? bir : (g == 1) ? biz : bin;

    float acc[8][4];
#pragma unroll
    for (int i = 0; i < 8; ++i)
#pragma unroll
        for (int c = 0; c < 4; ++c) acc[i][c] = 0.0f;

    for (int k0 = 0; k0 < D; k0 += 32) {
        __syncthreads();
#pragma unroll
        for (int it = 0; it < 4; ++it) {
            int l4 = tid + it * 256;
            int m = l4 >> 3, k4 = l4 & 7;
            float4 v = *(const float4*)&X[(t0 + m) * D + k0 + (k4 << 2)];
            float* dst = &Xs[m * 33 + (k4 << 2)];
            dst[0] = v.x; dst[1] = v.y; dst[2] = v.z; dst[3] = v.w;
        }
#pragma unroll
        for (int it = 0; it < 2; ++it) {
            int l4 = tid + it * 256;
            int k = l4 >> 4, j4 = l4 & 15;
            *(float4*)&Ws[k * 64 + (j4 << 2)] =
                *(const float4*)&W[(k0 + k) * D + j0 + (j4 << 2)];
        }
        __syncthreads();
#pragma unroll
        for (int kk = 0; kk < 32; ++kk) {
            float4 wv = *(float4*)&Ws[kk * 64 + (tx << 2)];
#pragma unroll
            for (int i = 0; i < 8; ++i) {
                float x = Xs[(ty * 8 + i) * 33 + kk];
                acc[i][0] += x * wv.x;
                acc[i][1] += x * wv.y;
                acc[i][2] += x * wv.z;
                acc[i][3] += x * wv.w;
            }
        }
    }

    float4 bv = *(const float4*)&bias[j0 + (tx << 2)];
#pragma unroll
    for (int i = 0; i < 8; ++i) {
        int t = t0 + ty * 8 + i;
        float4 o;
        o.x = acc[i][0] + bv.x;
        o.y = acc[i][1] + bv.y;
        o.z = acc[i][2] + bv.z;
        o.w = acc[i][3] + bv.w;
        *(float4*)&gi[t * GI_STRIDE + g * D + j0 + (tx << 2)] = o;
    }
}

// ---------------------------------------------------------------------------
// Kernel B: parallel segment extraction + counting sort by length (desc).
// ---------------------------------------------------------------------------
__global__ void kB(const int* __restrict__ term,
                   int* __restrict__ st_sorted, int* __restrict__ n_active,
                   int* __restrict__ nseg_out, int* __restrict__ maxlen_out)
{
    __shared__ unsigned long long masks[16];
    __shared__ int hist[1025];
    __shared__ int off[1025];
    __shared__ int cur[1025];
    __shared__ int sh_maxlen;
    const int tid = threadIdx.x;
    if (tid == 0) sh_maxlen = 0;
    for (int i = tid; i < 1025; i += 256) { hist[i] = 0; cur[i] = 0; }
    __syncthreads();

    const int wid = tid >> 6;
#pragma unroll
    for (int it = 0; it < 4; ++it) {
        int t = it * 256 + tid;
        bool f = (t == 0) || (term[t] != 0);
        unsigned long long m = __ballot(f);
        if ((tid & 63) == 0) masks[it * 4 + wid] = m;
    }
    __syncthreads();

    int myt[4], mylen[4], cnt = 0;
#pragma unroll
    for (int it = 0; it < 4; ++it) {
        int t = it * 256 + tid;
        int w0 = t >> 6, b = t & 63;
        if ((masks[w0] >> b) & 1ULL) {
            int next = T;
            unsigned long long m = masks[w0] & ~((2ULL << b) - 1ULL);
            if (m) next = (w0 << 6) + __builtin_ctzll(m);
            else {
                for (int w = w0 + 1; w < 16; ++w)
                    if (masks[w]) { next = (w << 6) + __builtin_ctzll(masks[w]); break; }
            }
            int L = next - t;
            myt[cnt] = t; mylen[cnt] = L; ++cnt;
            atomicAdd(&hist[L], 1);
            atomicMax(&sh_maxlen, L);
        }
    }
    __syncthreads();
    if (tid == 0) {
        int run = 0, ml = sh_maxlen;
        for (int L = ml; L >= 1; --L) {
            off[L] = run;
            run += hist[L];
            n_active[L - 1] = run;   // #segments with len >= L  == active at step L-1
        }
        nseg_out[0] = run;
        maxlen_out[0] = ml;
    }
    __syncthreads();
    for (int c = 0; c < cnt; ++c) {
        int L = mylen[c];
        int pos = off[L] + atomicAdd(&cur[L], 1);
        st_sorted[pos] = myt[c];
    }
}

// ---------------------------------------------------------------------------
// Kernel B2: initialize H row p (sorted order).
// ---------------------------------------------------------------------------
__global__ void kB2(const float* __restrict__ last_state, const int* __restrict__ term,
                    const int* __restrict__ st_sorted, const int* __restrict__ nseg_p,
                    float* __restrict__ Hb0)
{
    int p = blockIdx.x;
    if (p >= nseg_p[0]) return;
    bool useLast = (st_sorted[p] == 0) && (term[0] == 0);
    for (int j = threadIdx.x; j < D; j += 256)
        Hb0[p * D + j] = useLast ? last_state[j] : 0.0f;
}

// ---------------------------------------------------------------------------
// Kernel C (cooperative): macro-step loop with adaptive split-K.
// FIX vs round 2: ks guard compares TILE count (mtiles*32*ks) to grid size;
// the previous rows_pad*32*ks was 32x too big so ks was always 1.
// Per step now: tiles ~= G for every step; tail steps get ks=16 (Klen=128).
// ---------------------------------------------------------------------------
__global__ __launch_bounds__(256, 2) void kC(
    const float* __restrict__ whr, const float* __restrict__ whz, const float* __restrict__ whn,
    const float* __restrict__ bhn, const float* __restrict__ gi,
    float* __restrict__ Hb0, float* __restrict__ Hb1,
    const int* __restrict__ st, const int* __restrict__ n_active,
    const int* __restrict__ maxlen_p, float* __restrict__ part,
    float* __restrict__ out)
{
    cg::grid_group grid = cg::this_grid();
    __shared__ float Hs[32 * 33];
    __shared__ float Wrs[32 * 64];
    __shared__ float Wzs[32 * 64];
    __shared__ float Wns[32 * 64];

    const int tid = threadIdx.x;
    const int tx = tid & 15;   // j group (4 cols)
    const int ty = tid >> 4;   // m group (2 rows)
    const int maxlen = maxlen_p[0];
    const int G = gridDim.x;

    for (int s = 0; s < maxlen; ++s) {
        const float* __restrict__ Hc = (s & 1) ? Hb1 : Hb0;
        float* __restrict__ Hn = (s & 1) ? Hb0 : Hb1;
        const int active = n_active[s];
        const int mtiles = (active + 31) >> 5;
        const int rows_pad = mtiles << 5;

        int ks = 1;
        while (ks < 16 && mtiles * 32 * ks < G && mtiles * ks * 2 <= 16) ks <<= 1;
        const int Klen = D / ks;
        const int tiles = mtiles * 32 * ks;

        for (int tile = blockIdx.x; tile < tiles; tile += G) {
            const int kidx = tile / (mtiles * 32);
            const int rem  = tile - kidx * (mtiles * 32);
            const int p0 = (rem >> 5) << 5;
            const int j0 = (rem & 31) << 6;
            const int kbeg = kidx * Klen;

            float ar[2][4], az[2][4], an[2][4];
#pragma unroll
            for (int i = 0; i < 2; ++i)
#pragma unroll
                for (int c = 0; c < 4; ++c) { ar[i][c] = 0.f; az[i][c] = 0.f; an[i][c] = 0.f; }

            for (int k0 = kbeg; k0 < kbeg + Klen; k0 += 32) {
                __syncthreads();
                {   // stage H tile: 32 x 32, one float4/thread
                    int m = tid >> 3, k4 = (tid & 7) << 2;
                    float4 v = *(const float4*)&Hc[(size_t)(p0 + m) * D + k0 + k4];
                    float* dst = &Hs[m * 33 + k4];
                    dst[0] = v.x; dst[1] = v.y; dst[2] = v.z; dst[3] = v.w;
                }
#pragma unroll
                for (int it = 0; it < 2; ++it) {   // stage 3 W tiles: 32 x 64
                    int l4 = tid + it * 256;
                    int k = l4 >> 4, j4 = (l4 & 15) << 2;
                    size_t ga = (size_t)(k0 + k) * D + j0 + j4;
                    int la = k * 64 + j4;
                    *(float4*)&Wrs[la] = *(const float4*)&whr[ga];
                    *(float4*)&Wzs[la] = *(const float4*)&whz[ga];
                    *(float4*)&Wns[la] = *(const float4*)&whn[ga];
                }
                __syncthreads();
#pragma unroll
                for (int kk = 0; kk < 32; ++kk) {
                    float4 wr = *(float4*)&Wrs[kk * 64 + (tx << 2)];
                    float4 wz = *(float4*)&Wzs[kk * 64 + (tx << 2)];
                    float4 wn = *(float4*)&Wns[kk * 64 + (tx << 2)];
#pragma unroll
                    for (int i = 0; i < 2; ++i) {
                        float h = Hs[(ty * 2 + i) * 33 + kk];
                        ar[i][0] += h * wr.x; ar[i][1] += h * wr.y;
                        ar[i][2] += h * wr.z; ar[i][3] += h * wr.w;
                        az[i][0] += h * wz.x; az[i][1] += h * wz.y;
                        az[i][2] += h * wz.z; az[i][3] += h * wz.w;
                        an[i][0] += h * wn.x; an[i][1] += h * wn.y;
                        an[i][2] += h * wn.z; an[i][3] += h * wn.w;
                    }
                }
            }

            if (ks == 1) {
#pragma unroll
                for (int i = 0; i < 2; ++i) {
                    int p = p0 + ty * 2 + i;
                    if (p < active) {
                        int t = st[p] + s;
                        int j = j0 + (tx << 2);
                        const float4 gr = *(const float4*)&gi[(size_t)t * GI_STRIDE + j];
                        const float4 gz = *(const float4*)&gi[(size_t)t * GI_STRIDE + D + j];
                        const float4 gn = *(const float4*)&gi[(size_t)t * GI_STRIDE + 2 * D + j];
                        const float4 bh = *(const float4*)&bhn[j];
                        const float4 ho = *(const float4*)&Hc[(size_t)p * D + j];
                        float4 h4;
                        {
                            float r = sigf(ar[i][0] + gr.x);
                            float z = sigf(az[i][0] + gz.x);
                            float nn = tanhfast(gn.x + r * (an[i][0] + bh.x));
                            h4.x = (1.0f - z) * nn + z * ho.x;
                        }
                        {
                            float r = sigf(ar[i][1] + gr.y);
                            float z = sigf(az[i][1] + gz.y);
                            float nn = tanhfast(gn.y + r * (an[i][1] + bh.y));
                            h4.y = (1.0f - z) * nn + z * ho.y;
                        }
                        {
                            float r = sigf(ar[i][2] + gr.z);
                            float z = sigf(az[i][2] + gz.z);
                            float nn = tanhfast(gn.z + r * (an[i][2] + bh.z));
                            h4.z = (1.0f - z) * nn + z * ho.z;
                        }
                        {
                            float r = sigf(ar[i][3] + gr.w);
                            float z = sigf(az[i][3] + gz.w);
                            float nn = tanhfast(gn.w + r * (an[i][3] + bh.w));
                            h4.w = (1.0f - z) * nn + z * ho.w;
                        }
                        *(float4*)&Hn[(size_t)p * D + j] = h4;
                        *(float4*)&out[(size_t)t * D + j] = h4;
                        *(float4*)&out[(size_t)(T + t) * D + j] = h4;
                    }
                }
            } else {
#pragma unroll
                for (int i = 0; i < 2; ++i) {
                    int p = p0 + ty * 2 + i;
                    int j = j0 + (tx << 2);
                    size_t base = (size_t)(kidx * rows_pad + p) * 3 * D + j;
                    float4 v;
                    v.x = ar[i][0]; v.y = ar[i][1]; v.z = ar[i][2]; v.w = ar[i][3];
                    *(float4*)&part[base] = v;
                    v.x = az[i][0]; v.y = az[i][1]; v.z = az[i][2]; v.w = az[i][3];
                    *(float4*)&part[base + D] = v;
                    v.x = an[i][0]; v.y = an[i][1]; v.z = an[i][2]; v.w = an[i][3];
                    *(float4*)&part[base + 2 * D] = v;
                }
            }
        }

        if (ks > 1) {
            __threadfence();
            grid.sync();
            // phase 2: reduce partials + gate math. One float4 column group/iter.
            const int gtid = blockIdx.x * 256 + tid;
            const int total = active << 9;  // active rows * 512 float4-groups
            for (int idx = gtid; idx < total; idx += G * 256) {
                const int p = idx >> 9;
                const int j = (idx & 511) << 2;
                const int t = st[p] + s;
                float srx = 0, sry = 0, srz = 0, srw = 0;
                float szx = 0, szy = 0, szz = 0, szw = 0;
                float snx = 0, sny = 0, snz = 0, snw = 0;
                for (int kq = 0; kq < ks; ++kq) {
                    size_t base = (size_t)(kq * rows_pad + p) * 3 * D + j;
                    float4 a = *(const float4*)&part[base];
                    float4 b = *(const float4*)&part[base + D];
                    float4 c = *(const float4*)&part[base + 2 * D];
                    srx += a.x; sry += a.y; srz += a.z; srw += a.w;
                    szx += b.x; szy += b.y; szz += b.z; szw += b.w;
                    snx += c.x; sny += c.y; snz += c.z; snw += c.w;
                }
                const float4 gr = *(const float4*)&gi[(size_t)t * GI_STRIDE + j];
                const float4 gz = *(const float4*)&gi[(size_t)t * GI_STRIDE + D + j];
                const float4 gn = *(const float4*)&gi[(size_t)t * GI_STRIDE + 2 * D + j];
                const float4 bh = *(const float4*)&bhn[j];
                const float4 ho = *(const float4*)&Hc[(size_t)p * D + j];
                float4 h4;
                {
                    float r = sigf(srx + gr.x);
                    float z = sigf(szx + gz.x);
                    float nn = tanhfast(gn.x + r * (snx + bh.x));
                    h4.x = (1.0f - z) * nn + z * ho.x;
                }
                {
                    float r = sigf(sry + gr.y);
                    float z = sigf(szy + gz.y);
                    float nn = tanhfast(gn.y + r * (sny + bh.y));
                    h4.y = (1.0f - z) * nn + z * ho.y;
                }
                {
                    float r = sigf(srz + gr.z);
                    float z = sigf(szz + gz.z);
                    float nn = tanhfast(gn.z + r * (snz + bh.z));
                    h4.z = (1.0f - z) * nn + z * ho.z;
                }
                {
                    float r = sigf(srw + gr.w);
                    float z = sigf(szw + gz.w);
                    float nn = tanhfast(gn.w + r * (snw + bh.w));
                    h4.w = (1.0f - z) * nn + z * ho.w;
                }
                *(float4*)&Hn[(size_t)p * D + j] = h4;
                *(float4*)&out[(size_t)t * D + j] = h4;
                *(float4*)&out[(size_t)(T + t) * D + j] = h4;
            }
        }
        __threadfence();
        grid.sync();
    }
}

// ---------------------------------------------------------------------------
extern "C" void kernel_launch(void* const* d_in, const int* in_sizes, int n_in,
                              void* d_out, int out_size, void* d_ws, size_t ws_size,
                              hipStream_t stream)
{
    const float* X    = (const float*)d_in[0];
    const int*   term = (const int*)  d_in[1];
    const float* last = (const float*)d_in[2];
    const float* wir  = (const float*)d_in[3];
    const float* wiz  = (const float*)d_in[4];
    const float* win  = (const float*)d_in[5];
    const float* bir  = (const float*)d_in[6];
    const float* biz  = (const float*)d_in[7];
    const float* bin  = (const float*)d_in[8];
    const float* whr  = (const float*)d_in[9];
    const float* whz  = (const float*)d_in[10];
    const float* whn  = (const float*)d_in[11];
    const float* bhn  = (const float*)d_in[12];
    float* out = (float*)d_out;

    char* ws = (char*)d_ws;
    size_t off = 0;
    float* gi  = (float*)(ws + off); off += (size_t)T * GI_STRIDE * 4;   // 24 MB
    float* hb0 = (float*)(ws + off); off += (size_t)T * D * 4;           // 8 MB
    float* hb1 = (float*)(ws + off); off += (size_t)T * D * 4;           // 8 MB
    float* part = (float*)(ws + off); off += (size_t)512 * 3 * D * 4;    // 12.6 MB
    int* meta = (int*)(ws + off);
    int* st       = meta;            // 1024
    int* n_active = meta + 1024;     // 1024
    int* nseg_p   = meta + 2048;
    int* maxlen_p = meta + 2049;

    kA<<<dim3(96, 8), 256, 0, stream>>>(X, wir, wiz, win, bir, biz, bin, gi);
    kB<<<1, 256, 0, stream>>>(term, st, n_active, nseg_p, maxlen_p);
    kB2<<<1024, 256, 0, stream>>>(last, term, st, nseg_p, hb0);

    int maxB = 0;
    if (hipOccupancyMaxActiveBlocksPerMultiprocessor(&maxB, kC, 256, 0) != hipSuccess || maxB < 1)
        maxB = 1;
    int grid = maxB * 256;
    if (grid > 512) grid = 512;

    const float* c_whr = whr; const float* c_whz = whz; const float* c_whn = whn;
    const float* c_bhn = bhn; const float* c_gi = gi;
    float* c_h0 = hb0; float* c_h1 = hb1;
    const int* c_st = st; const int* c_na = n_active; const int* c_ml = maxlen_p;
    float* c_part = part; float* c_out = out;
    void* args[] = {&c_whr, &c_whz, &c_whn, &c_bhn, &c_gi, &c_h0, &c_h1,
                    &c_st, &c_na, &c_ml, &c_part, &c_out};
    hipLaunchCooperativeKernel((void*)kC, dim3(grid), dim3(256), args, 0, stream);
}

// Round 6
// 2167.784 us; speedup vs baseline: 1.1577x; 1.1577x over previous
//
#include <hip/hip_runtime.h>
#include <hip/hip_cooperative_groups.h>

namespace cg = cooperative_groups;

#define D 2048
#define T 1024
#define NG 6144            // 3 * D
#define NSLICE 384         // 6144 / 16 column-slices

typedef short bf16x8 __attribute__((ext_vector_type(8)));
typedef float f32x4 __attribute__((ext_vector_type(4)));

__device__ __forceinline__ float sigf(float x) {
    return 1.0f / (1.0f + __expf(-x));
}
__device__ __forceinline__ float tanhfast(float x) {
    float e = __expf(-2.0f * fabsf(x));
    float t = (1.0f - e) / (1.0f + e);
    return copysignf(t, x);
}
// fp32 -> bf16 round-to-nearest-even
__device__ __forceinline__ unsigned short f2bf(float x) {
    unsigned int u = __float_as_uint(x);
    return (unsigned short)((u + 0x7FFFu + ((u >> 16) & 1u)) >> 16);
}
__device__ __forceinline__ float4 bfu4(ushort4 u) {
    float4 f;
    f.x = __uint_as_float((unsigned int)u.x << 16);
    f.y = __uint_as_float((unsigned int)u.y << 16);
    f.z = __uint_as_float((unsigned int)u.z << 16);
    f.w = __uint_as_float((unsigned int)u.w << 16);
    return f;
}

// XOR-swizzled LDS position for weight slice Ws[16 n][2048 k] (bf16).
// Keeps 16B granules intact; b-frag ds_read_b128 conflict-free.
__device__ __forceinline__ int swiz(int n, int k) {
    return n * 2048 + (((k & ~7) ^ (n * 8)) | (k & 7));
}

// load + convert + transpose-swizzle one 16-col weight slice into LDS
__device__ __forceinline__ void loadSlice(unsigned short* Ws, int sl,
    const float* __restrict__ whr, const float* __restrict__ whz,
    const float* __restrict__ whn, int tid)
{
    const int n0 = sl * 16;
    const float* __restrict__ wg = (n0 < 2048) ? whr : (n0 < 4096) ? whz : whn;
    const int j0 = n0 & 2047;
    const int tn = tid & 15, tk0 = tid >> 4;
    for (int k = tk0; k < 2048; k += 16)
        Ws[swiz(tn, k)] = f2bf(wg[(size_t)k * D + j0 + tn]);
}

// ---------------------------------------------------------------------------
// kX: X fp32 -> bf16
// ---------------------------------------------------------------------------
__global__ void kX(const float* __restrict__ X, unsigned short* __restrict__ Xh) {
    int idx = blockIdx.x * 256 + threadIdx.x;          // float4 groups
    const int total = T * D / 4;
    for (; idx < total; idx += gridDim.x * 256) {
        float4 v = *(const float4*)&X[idx * 4];
        ushort4 o;
        o.x = f2bf(v.x); o.y = f2bf(v.y); o.z = f2bf(v.z); o.w = f2bf(v.w);
        *(ushort4*)&Xh[idx * 4] = o;
    }
}

// ---------------------------------------------------------------------------
// kB: parallel segment extraction + counting sort by length (desc).
// ---------------------------------------------------------------------------
__global__ void kB(const int* __restrict__ term,
                   int* __restrict__ st_sorted, int* __restrict__ n_active,
                   int* __restrict__ nseg_out, int* __restrict__ maxlen_out)
{
    __shared__ unsigned long long masks[16];
    __shared__ int hist[1025];
    __shared__ int off[1025];
    __shared__ int cur[1025];
    __shared__ int sh_maxlen;
    const int tid = threadIdx.x;
    if (tid == 0) sh_maxlen = 0;
    for (int i = tid; i < 1025; i += 256) { hist[i] = 0; cur[i] = 0; }
    __syncthreads();

    const int wid = tid >> 6;
#pragma unroll
    for (int it = 0; it < 4; ++it) {
        int t = it * 256 + tid;
        bool f = (t == 0) || (term[t] != 0);
        unsigned long long m = __ballot(f);
        if ((tid & 63) == 0) masks[it * 4 + wid] = m;
    }
    __syncthreads();

    int myt[4], mylen[4], cnt = 0;
#pragma unroll
    for (int it = 0; it < 4; ++it) {
        int t = it * 256 + tid;
        int w0 = t >> 6, b = t & 63;
        if ((masks[w0] >> b) & 1ULL) {
            int next = T;
            unsigned long long m = masks[w0] & ~((2ULL << b) - 1ULL);
            if (m) next = (w0 << 6) + __builtin_ctzll(m);
            else {
                for (int w = w0 + 1; w < 16; ++w)
                    if (masks[w]) { next = (w << 6) + __builtin_ctzll(masks[w]); break; }
            }
            int L = next - t;
            myt[cnt] = t; mylen[cnt] = L; ++cnt;
            atomicAdd(&hist[L], 1);
            atomicMax(&sh_maxlen, L);
        }
    }
    __syncthreads();
    if (tid == 0) {
        int run = 0, ml = sh_maxlen;
        for (int L = ml; L >= 1; --L) {
            off[L] = run;
            run += hist[L];
            n_active[L - 1] = run;   // #segments with len >= L == active at step L-1
        }
        nseg_out[0] = run;
        maxlen_out[0] = ml;
    }
    __syncthreads();
    for (int c = 0; c < cnt; ++c) {
        int L = mylen[c];
        int pos = off[L] + atomicAdd(&cur[L], 1);
        st_sorted[pos] = myt[c];
    }
}

// ---------------------------------------------------------------------------
// kB2: init H row p (fp32 + bf16 shadow), sorted order.
// ---------------------------------------------------------------------------
__global__ void kB2(const float* __restrict__ last_state, const int* __restrict__ term,
                    const int* __restrict__ st_sorted, const int* __restrict__ nseg_p,
                    float* __restrict__ Hb, unsigned short* __restrict__ Hh)
{
    int p = blockIdx.x;
    if (p >= nseg_p[0]) return;
    bool useLast = (st_sorted[p] == 0) && (term[0] == 0);
    for (int j = threadIdx.x; j < D; j += 256) {
        float v = useLast ? last_state[j] : 0.0f;
        Hb[(size_t)p * D + j] = v;
        Hh[(size_t)p * D + j] = f2bf(v);
    }
}

// ---------------------------------------------------------------------------
// kA2: input projections via LDS weight slice + MFMA (regular launch, 384 blk).
// gih[t][n] = bf16( X[t,:] @ Wi_g[:,j] + bias_g[j] )
// ---------------------------------------------------------------------------
__global__ __launch_bounds__(256, 2) void kA2(
    const unsigned short* __restrict__ Xh,
    const float* __restrict__ wir, const float* __restrict__ wiz, const float* __restrict__ win,
    const float* __restrict__ bir, const float* __restrict__ biz, const float* __restrict__ bin,
    unsigned short* __restrict__ gih)
{
    __shared__ __align__(16) unsigned short Ws[16 * 2048];
    const int tid = threadIdx.x;
    const int lane = tid & 63, wave = tid >> 6;
    const int mlane = lane & 15, quad = lane >> 4;
    const int n0 = blockIdx.x * 16;
    const int g = n0 >> 11;
    const int j0 = n0 & 2047;
    const float* __restrict__ wg = (g == 0) ? wir : (g == 1) ? wiz : win;
    const float* __restrict__ bias = (g == 0) ? bir : (g == 1) ? biz : bin;

    {
        int tn = tid & 15, tk0 = tid >> 4;
        for (int k = tk0; k < 2048; k += 16)
            Ws[swiz(tn, k)] = f2bf(wg[(size_t)k * D + j0 + tn]);
    }
    __syncthreads();

    const float bv = bias[j0 + mlane];

    for (int m0 = 0; m0 < 64; m0 += 32) {
        f32x4 acc[8];
#pragma unroll
        for (int i = 0; i < 8; ++i) acc[i] = (f32x4){0.f, 0.f, 0.f, 0.f};

        const unsigned short* rowp[8];
#pragma unroll
        for (int i = 0; i < 8; ++i)
            rowp[i] = Xh + (size_t)((m0 + wave + 4 * i) * 16 + mlane) * D + quad * 8;

        for (int kc = 0; kc < 64; ++kc) {
            bf16x8 b = *(const bf16x8*)&Ws[swiz(mlane, kc * 32 + quad * 8)];
#pragma unroll
            for (int i = 0; i < 8; ++i) {
                bf16x8 a = *(const bf16x8*)(rowp[i] + kc * 32);
                acc[i] = __builtin_amdgcn_mfma_f32_16x16x32_bf16(a, b, acc[i], 0, 0, 0);
            }
        }
#pragma unroll
        for (int i = 0; i < 8; ++i) {
            int rbase = (m0 + wave + 4 * i) * 16 + quad * 4;
#pragma unroll
            for (int r = 0; r < 4; ++r)
                gih[(size_t)(rbase + r) * NG + n0 + mlane] = f2bf(acc[i][r] + bv);
        }
    }
}

// ---------------------------------------------------------------------------
// kC (cooperative): LDS-resident recurrent weight slices + MFMA macro-steps.
// Grid G = min(NSLICE, occupancy capacity); block b owns slices {b, b+G, ...}
// (reload only when switching — zero reloads when G == NSLICE).
// ---------------------------------------------------------------------------
__global__ __launch_bounds__(256, 2) void kC(
    const float* __restrict__ whr, const float* __restrict__ whz, const float* __restrict__ whn,
    const float* __restrict__ bhn, const unsigned short* __restrict__ gih,
    float* __restrict__ Hb, unsigned short* __restrict__ Hh,
    const int* __restrict__ st, const int* __restrict__ n_active,
    const int* __restrict__ maxlen_p, float* __restrict__ pre,
    float* __restrict__ out)
{
    __shared__ __align__(16) unsigned short Ws[16 * 2048];
    const int tid = threadIdx.x;
    const int lane = tid & 63, wave = tid >> 6;
    const int mlane = lane & 15, quad = lane >> 4;
    const int G = gridDim.x;

    int cur = blockIdx.x;
    loadSlice(Ws, cur, whr, whz, whn, tid);
    __syncthreads();

    cg::grid_group grid = cg::this_grid();
    const int maxlen = maxlen_p[0];

    for (int s = 0; s < maxlen; ++s) {
        const int active = n_active[s];
        const int mtiles = (active + 15) >> 4;

        // ---- phase 1: preactivations pre[p][n] = Hh[p,:] @ Wh (slice cols) ----
        for (int sl = blockIdx.x; sl < NSLICE; sl += G) {
            if (sl != cur) {
                __syncthreads();
                loadSlice(Ws, sl, whr, whz, whn, tid);
                cur = sl;
                __syncthreads();
            }
            const int n0 = sl * 16;

            if (mtiles >= 3) {
                for (int m0 = 0; m0 < mtiles; m0 += 32) {
                    const int nmt = min(32, mtiles - m0);
                    f32x4 acc[8];
#pragma unroll
                    for (int i = 0; i < 8; ++i) acc[i] = (f32x4){0.f, 0.f, 0.f, 0.f};
                    const unsigned short* rowp[8];
#pragma unroll
                    for (int i = 0; i < 8; ++i)
                        rowp[i] = Hh + (size_t)((m0 + wave + 4 * i) * 16 + mlane) * D + quad * 8;

                    for (int kc = 0; kc < 64; ++kc) {
                        bf16x8 b = *(const bf16x8*)&Ws[swiz(mlane, kc * 32 + quad * 8)];
#pragma unroll
                        for (int i = 0; i < 8; ++i) {
                            if (wave + 4 * i < nmt) {
                                bf16x8 a = *(const bf16x8*)(rowp[i] + kc * 32);
                                acc[i] = __builtin_amdgcn_mfma_f32_16x16x32_bf16(a, b, acc[i], 0, 0, 0);
                            }
                        }
                    }
#pragma unroll
                    for (int i = 0; i < 8; ++i) {
                        if (wave + 4 * i < nmt) {
                            int rbase = (m0 + wave + 4 * i) * 16 + quad * 4;
#pragma unroll
                            for (int r = 0; r < 4; ++r)
                                pre[(size_t)(rbase + r) * NG + n0 + mlane] = acc[i][r];
                        }
                    }
                }
            } else if (wave < mtiles) {
                // tail path: 1-2 m-tiles; batch kc in groups of 8 to hide latency
                f32x4 acc = (f32x4){0.f, 0.f, 0.f, 0.f};
                const unsigned short* hrow =
                    Hh + (size_t)(wave * 16 + mlane) * D + quad * 8;
                for (int kg = 0; kg < 8; ++kg) {
                    bf16x8 a[8], b[8];
#pragma unroll
                    for (int u = 0; u < 8; ++u) {
                        int kc = kg * 8 + u;
                        a[u] = *(const bf16x8*)(hrow + kc * 32);
                        b[u] = *(const bf16x8*)&Ws[swiz(mlane, kc * 32 + quad * 8)];
                    }
#pragma unroll
                    for (int u = 0; u < 8; ++u)
                        acc = __builtin_amdgcn_mfma_f32_16x16x32_bf16(a[u], b[u], acc, 0, 0, 0);
                }
                int rbase = wave * 16 + quad * 4;
#pragma unroll
                for (int r = 0; r < 4; ++r)
                    pre[(size_t)(rbase + r) * NG + n0 + mlane] = acc[r];
            }
        }

        __threadfence();
        grid.sync();

        // ---- phase 2: gate math, flat over active*512 float4 groups ----
        {
            int idx = blockIdx.x * 256 + tid;
            const int total = active << 9;
            for (; idx < total; idx += G * 256) {
                const int p = idx >> 9;
                const int j = (idx & 511) << 2;
                const int t = st[p] + s;
                const float4 pr = *(const float4*)&pre[(size_t)p * NG + j];
                const float4 pz = *(const float4*)&pre[(size_t)p * NG + D + j];
                const float4 pn = *(const float4*)&pre[(size_t)p * NG + 2 * D + j];
                const float4 gr = bfu4(*(const ushort4*)&gih[(size_t)t * NG + j]);
                const float4 gz = bfu4(*(const ushort4*)&gih[(size_t)t * NG + D + j]);
                const float4 gn = bfu4(*(const ushort4*)&gih[(size_t)t * NG + 2 * D + j]);
                const float4 bh = *(const float4*)&bhn[j];
                const float4 ho = *(const float4*)&Hb[(size_t)p * D + j];
                float4 h4;
                {
                    float r = sigf(pr.x + gr.x);
                    float z = sigf(pz.x + gz.x);
                    float nn = tanhfast(gn.x + r * (pn.x + bh.x));
                    h4.x = (1.0f - z) * nn + z * ho.x;
                }
                {
                    float r = sigf(pr.y + gr.y);
                    float z = sigf(pz.y + gz.y);
                    float nn = tanhfast(gn.y + r * (pn.y + bh.y));
                    h4.y = (1.0f - z) * nn + z * ho.y;
                }
                {
                    float r = sigf(pr.z + gr.z);
                    float z = sigf(pz.z + gz.z);
                    float nn = tanhfast(gn.z + r * (pn.z + bh.z));
                    h4.z = (1.0f - z) * nn + z * ho.z;
                }
                {
                    float r = sigf(pr.w + gr.w);
                    float z = sigf(pz.w + gz.w);
                    float nn = tanhfast(gn.w + r * (pn.w + bh.w));
                    h4.w = (1.0f - z) * nn + z * ho.w;
                }
                *(float4*)&Hb[(size_t)p * D + j] = h4;
                ushort4 hh;
                hh.x = f2bf(h4.x); hh.y = f2bf(h4.y);
                hh.z = f2bf(h4.z); hh.w = f2bf(h4.w);
                *(ushort4*)&Hh[(size_t)p * D + j] = hh;
                *(float4*)&out[(size_t)t * D + j] = h4;
                *(float4*)&out[(size_t)(T + t) * D + j] = h4;
            }
        }

        __threadfence();
        grid.sync();
    }
}

// ---------------------------------------------------------------------------
// Workspace layout (total 50.36 MB — below round-3's proven 52.7 MB usage):
//   [0, 16K)        meta: st(1024) | n_active(1024) | nseg | maxlen
//   [16K, +12.58M)  gih  (T x NG bf16)
//   [.., +8.39M)    Hb   (T x D fp32)
//   [.., +4.19M)    Hh   (T x D bf16)
//   [.., +25.17M)   pre  (T x NG fp32)  -- head aliased as Xh (T x D bf16);
//                                          Xh dead after kA2, pre written after.
// ---------------------------------------------------------------------------
extern "C" void kernel_launch(void* const* d_in, const int* in_sizes, int n_in,
                              void* d_out, int out_size, void* d_ws, size_t ws_size,
                              hipStream_t stream)
{
    const float* X    = (const float*)d_in[0];
    const int*   term = (const int*)  d_in[1];
    const float* last = (const float*)d_in[2];
    const float* wir  = (const float*)d_in[3];
    const float* wiz  = (const float*)d_in[4];
    const float* win  = (const float*)d_in[5];
    const float* bir  = (const float*)d_in[6];
    const float* biz  = (const float*)d_in[7];
    const float* bin  = (const float*)d_in[8];
    const float* whr  = (const float*)d_in[9];
    const float* whz  = (const float*)d_in[10];
    const float* whn  = (const float*)d_in[11];
    const float* bhn  = (const float*)d_in[12];
    float* out = (float*)d_out;

    char* ws = (char*)d_ws;
    int* meta = (int*)ws;
    int* st       = meta;
    int* n_active = meta + 1024;
    int* nseg_p   = meta + 2048;
    int* maxlen_p = meta + 2049;
    size_t off = 16384;
    unsigned short* gih = (unsigned short*)(ws + off); off += (size_t)T * NG * 2;  // 12.58 MB
    float* Hb  = (float*)(ws + off); off += (size_t)T * D * 4;                     // 8.39 MB
    unsigned short* Hh = (unsigned short*)(ws + off); off += (size_t)T * D * 2;    // 4.19 MB
    float* pre = (float*)(ws + off);                                               // 25.17 MB
    unsigned short* Xh = (unsigned short*)pre;   // alias: Xh dead after kA2

    kX<<<512, 256, 0, stream>>>(X, Xh);
    kB<<<1, 256, 0, stream>>>(term, st, n_active, nseg_p, maxlen_p);
    kB2<<<1024, 256, 0, stream>>>(last, term, st, nseg_p, Hb, Hh);
    kA2<<<NSLICE, 256, 0, stream>>>(Xh, wir, wiz, win, bir, biz, bin, gih);

    // Cooperative grid sized to what can actually co-reside (64 KiB LDS/block
    // may cap occupancy at 1 block/CU => capacity 256 < 384; the slice loop
    // in kC handles any G <= NSLICE).
    int maxB = 0;
    if (hipOccupancyMaxActiveBlocksPerMultiprocessor(&maxB, kC, 256, 0) != hipSuccess || maxB < 1)
        maxB = 1;
    int G = maxB * 256;
    if (G > NSLICE) G = NSLICE;

    const float* c_whr = whr; const float* c_whz = whz; const float* c_whn = whn;
    const float* c_bhn = bhn; const unsigned short* c_gih = gih;
    float* c_hb = Hb; unsigned short* c_hh = Hh;
    const int* c_st = st; const int* c_na = n_active; const int* c_ml = maxlen_p;
    float* c_pre = pre; float* c_out = out;
    void* args[] = {&c_whr, &c_whz, &c_whn, &c_bhn, &c_gih, &c_hb, &c_hh,
                    &c_st, &c_na, &c_ml, &c_pre, &c_out};
    hipLaunchCooperativeKernel((void*)kC, dim3(G), dim3(256), args, 0, stream);
}

// Round 7
// 917.395 us; speedup vs baseline: 2.7355x; 2.3630x over previous
//
#include <hip/hip_runtime.h>

#define D 2048
#define T 1024
#define NG 6144            // 3 * D
#define KC_BLOCKS 128      // one 16-col j-group per block

typedef short bf16x8 __attribute__((ext_vector_type(8)));
typedef float f32x4 __attribute__((ext_vector_type(4)));

__device__ __forceinline__ float sigf(float x) {
    return 1.0f / (1.0f + __expf(-x));
}
__device__ __forceinline__ float tanhfast(float x) {
    float e = __expf(-2.0f * fabsf(x));
    float t = (1.0f - e) / (1.0f + e);
    return copysignf(t, x);
}
// fp32 -> bf16 round-to-nearest-even
__device__ __forceinline__ unsigned short f2bf(float x) {
    unsigned int u = __float_as_uint(x);
    return (unsigned short)((u + 0x7FFFu + ((u >> 16) & 1u)) >> 16);
}
__device__ __forceinline__ float bf2f(unsigned short h) {
    return __uint_as_float((unsigned int)h << 16);
}

// ---------------------------------------------------------------------------
// kX: X fp32 -> bf16
// ---------------------------------------------------------------------------
__global__ void kX(const float* __restrict__ X, unsigned short* __restrict__ Xh) {
    int idx = blockIdx.x * 256 + threadIdx.x;
    const int total = T * D / 4;
    for (; idx < total; idx += gridDim.x * 256) {
        float4 v = *(const float4*)&X[idx * 4];
        ushort4 o;
        o.x = f2bf(v.x); o.y = f2bf(v.y); o.z = f2bf(v.z); o.w = f2bf(v.w);
        *(ushort4*)&Xh[idx * 4] = o;
    }
}

// ---------------------------------------------------------------------------
// kW: transpose+convert 3 fp32 [k][j] matrices -> bf16 Wt[g][j][k].
// 64x64 tiles via LDS. grid (32, 32, 3).
// ---------------------------------------------------------------------------
__global__ __launch_bounds__(256) void kW(
    const float* __restrict__ w0, const float* __restrict__ w1, const float* __restrict__ w2,
    unsigned short* __restrict__ Wt)
{
    __shared__ unsigned short Ts[64][66];
    const int t = threadIdx.x;
    const int k0 = blockIdx.x * 64, j0 = blockIdx.y * 64, g = blockIdx.z;
    const float* __restrict__ src = (g == 0) ? w0 : (g == 1) ? w1 : w2;
    unsigned short* __restrict__ dst = Wt + (size_t)g * D * D;

#pragma unroll
    for (int q = 0; q < 4; ++q) {
        int id = q * 256 + t;
        int r = id >> 4, c4 = (id & 15) * 4;
        float4 v = *(const float4*)&src[(size_t)(k0 + r) * D + j0 + c4];
        Ts[r][c4 + 0] = f2bf(v.x);
        Ts[r][c4 + 1] = f2bf(v.y);
        Ts[r][c4 + 2] = f2bf(v.z);
        Ts[r][c4 + 3] = f2bf(v.w);
    }
    __syncthreads();
#pragma unroll
    for (int q = 0; q < 4; ++q) {
        int id = q * 256 + t;
        int jr = id >> 4, kc4 = (id & 15) * 4;
        ushort4 o;
        o.x = Ts[kc4 + 0][jr];
        o.y = Ts[kc4 + 1][jr];
        o.z = Ts[kc4 + 2][jr];
        o.w = Ts[kc4 + 3][jr];
        *(ushort4*)&dst[(size_t)(j0 + jr) * D + k0 + kc4] = o;
    }
}

// ---------------------------------------------------------------------------
// kB: parallel segment extraction + counting sort by length (desc).
// ---------------------------------------------------------------------------
__global__ void kB(const int* __restrict__ term,
                   int* __restrict__ st_sorted, int* __restrict__ n_active,
                   int* __restrict__ nseg_out, int* __restrict__ maxlen_out)
{
    __shared__ unsigned long long masks[16];
    __shared__ int hist[1025];
    __shared__ int off[1025];
    __shared__ int cur[1025];
    __shared__ int sh_maxlen;
    const int tid = threadIdx.x;
    if (tid == 0) sh_maxlen = 0;
    for (int i = tid; i < 1025; i += 256) { hist[i] = 0; cur[i] = 0; }
    __syncthreads();

    const int wid = tid >> 6;
#pragma unroll
    for (int it = 0; it < 4; ++it) {
        int t = it * 256 + tid;
        bool f = (t == 0) || (term[t] != 0);
        unsigned long long m = __ballot(f);
        if ((tid & 63) == 0) masks[it * 4 + wid] = m;
    }
    __syncthreads();

    int myt[4], mylen[4], cnt = 0;
#pragma unroll
    for (int it = 0; it < 4; ++it) {
        int t = it * 256 + tid;
        int w0 = t >> 6, b = t & 63;
        if ((masks[w0] >> b) & 1ULL) {
            int next = T;
            unsigned long long m = masks[w0] & ~((2ULL << b) - 1ULL);
            if (m) next = (w0 << 6) + __builtin_ctzll(m);
            else {
                for (int w = w0 + 1; w < 16; ++w)
                    if (masks[w]) { next = (w << 6) + __builtin_ctzll(masks[w]); break; }
            }
            int L = next - t;
            myt[cnt] = t; mylen[cnt] = L; ++cnt;
            atomicAdd(&hist[L], 1);
            atomicMax(&sh_maxlen, L);
        }
    }
    __syncthreads();
    if (tid == 0) {
        int run = 0, ml = sh_maxlen;
        for (int L = ml; L >= 1; --L) {
            off[L] = run;
            run += hist[L];
            n_active[L - 1] = run;   // #segments with len >= L == active at step L-1
        }
        nseg_out[0] = run;
        maxlen_out[0] = ml;
    }
    __syncthreads();
    for (int c = 0; c < cnt; ++c) {
        int L = mylen[c];
        int pos = off[L] + atomicAdd(&cur[L], 1);
        st_sorted[pos] = myt[c];
    }
}

// ---------------------------------------------------------------------------
// kB2: init H row p (fp32 + bf16 shadow in Hh0), sorted order.
// ---------------------------------------------------------------------------
__global__ void kB2(const float* __restrict__ last_state, const int* __restrict__ term,
                    const int* __restrict__ st_sorted, const int* __restrict__ nseg_p,
                    float* __restrict__ Hb, unsigned short* __restrict__ Hh0)
{
    int p = blockIdx.x;
    if (p >= nseg_p[0]) return;
    bool useLast = (st_sorted[p] == 0) && (term[0] == 0);
    for (int j = threadIdx.x; j < D; j += 256) {
        float v = useLast ? last_state[j] : 0.0f;
        Hb[(size_t)p * D + j] = v;
        Hh0[(size_t)p * D + j] = f2bf(v);
    }
}

// ---------------------------------------------------------------------------
// kA2: tiled bf16 GEMM gih = bf16(Xh @ Wi^T + bias). M=1024, N=6144, K=2048.
// 128x128 tile / block, 4 waves (2x2), 4x4 MFMA tiles/wave, BK=32.
// B is Wit[n][k] (pre-transposed bf16). grid (48, 8).
// ---------------------------------------------------------------------------
__global__ __launch_bounds__(256) void kA2(
    const unsigned short* __restrict__ Xh, const unsigned short* __restrict__ Wit,
    const float* __restrict__ bir, const float* __restrict__ biz, const float* __restrict__ bin,
    unsigned short* __restrict__ gih)
{
    __shared__ __align__(16) unsigned short As[128 * 32];
    __shared__ __align__(16) unsigned short Bs[128 * 32];
    const int t = threadIdx.x;
    const int lane = t & 63, wave = t >> 6;
    const int mlane = lane & 15, quad = lane >> 4;
    const int wm = wave & 1, wn = wave >> 1;
    const int n0 = blockIdx.x * 128, m0 = blockIdx.y * 128;

    f32x4 acc[4][4];
#pragma unroll
    for (int i = 0; i < 4; ++i)
#pragma unroll
        for (int j = 0; j < 4; ++j) acc[i][j] = (f32x4){0.f, 0.f, 0.f, 0.f};

    for (int k0 = 0; k0 < D; k0 += 32) {
        __syncthreads();
#pragma unroll
        for (int q = 0; q < 2; ++q) {
            int c = q * 256 + t;
            int row = c >> 2, k8 = (c & 3) * 8;
            *(bf16x8*)&As[c * 8] = *(const bf16x8*)&Xh[(size_t)(m0 + row) * D + k0 + k8];
            *(bf16x8*)&Bs[c * 8] = *(const bf16x8*)&Wit[(size_t)(n0 + row) * D + k0 + k8];
        }
        __syncthreads();
        bf16x8 a[4], b[4];
#pragma unroll
        for (int i = 0; i < 4; ++i)
            a[i] = *(const bf16x8*)&As[(wm * 64 + i * 16 + mlane) * 32 + quad * 8];
#pragma unroll
        for (int j = 0; j < 4; ++j)
            b[j] = *(const bf16x8*)&Bs[(wn * 64 + j * 16 + mlane) * 32 + quad * 8];
#pragma unroll
        for (int i = 0; i < 4; ++i)
#pragma unroll
            for (int j = 0; j < 4; ++j)
                acc[i][j] = __builtin_amdgcn_mfma_f32_16x16x32_bf16(a[i], b[j], acc[i][j], 0, 0, 0);
    }

    const int g = n0 >> 11;
    const float* __restrict__ bias = (g == 0) ? bir : (g == 1) ? biz : bin;
    float bv[4];
#pragma unroll
    for (int j = 0; j < 4; ++j)
        bv[j] = bias[(n0 & 2047) + wn * 64 + j * 16 + mlane];

#pragma unroll
    for (int i = 0; i < 4; ++i) {
#pragma unroll
        for (int j = 0; j < 4; ++j) {
            int ncol = n0 + wn * 64 + j * 16 + mlane;
#pragma unroll
            for (int r = 0; r < 4; ++r) {
                int mrow = m0 + wm * 64 + i * 16 + quad * 4 + r;
                gih[(size_t)mrow * NG + ncol] = f2bf(acc[i][j][r] + bv[j]);
            }
        }
    }
}

// ---------------------------------------------------------------------------
// flag-array grid barrier (no RMW contention).  sval must be unique/increasing.
// ---------------------------------------------------------------------------
__device__ __forceinline__ void gbar(int* flags, int* release, int sval) {
    __threadfence();
    __syncthreads();
    const int tid = threadIdx.x;
    if (blockIdx.x == 0) {
        if (tid > 0 && tid < (int)gridDim.x) {
            while (__hip_atomic_load(&flags[tid], __ATOMIC_ACQUIRE,
                                     __HIP_MEMORY_SCOPE_AGENT) != sval)
                __builtin_amdgcn_s_sleep(8);
        }
        __syncthreads();
        if (tid == 0)
            __hip_atomic_store(release, sval, __ATOMIC_RELEASE, __HIP_MEMORY_SCOPE_AGENT);
    } else {
        if (tid == 0) {
            __hip_atomic_store(&flags[blockIdx.x], sval, __ATOMIC_RELEASE,
                               __HIP_MEMORY_SCOPE_AGENT);
            while (__hip_atomic_load(release, __ATOMIC_ACQUIRE,
                                     __HIP_MEMORY_SCOPE_AGENT) != sval)
                __builtin_amdgcn_s_sleep(8);
        }
        __syncthreads();
    }
}

// ---------------------------------------------------------------------------
// kC (cooperative, 128 blocks): fused macro-step scan.
// Block owns 16 output columns (jg = blockIdx.x). Per step:
//   3-gate MFMA over k (b-frags straight from global Wht[j][k] bf16,
//   a-frags from ping-pong Hh), gate math in-register on C-frags,
//   writes Hb/Hnxt/out for its columns, ONE flag barrier.
// No LDS. Ping-pong Hh is WAR-safe: a block arrives only after its reads.
// ---------------------------------------------------------------------------
__global__ __launch_bounds__(256, 2) void kC(
    const unsigned short* __restrict__ Wht, const float* __restrict__ bhn,
    const unsigned short* __restrict__ gih,
    float* __restrict__ Hb,
    unsigned short* __restrict__ Hh0, unsigned short* __restrict__ Hh1,
    const int* __restrict__ st, const int* __restrict__ n_active,
    const int* __restrict__ maxlen_p,
    int* __restrict__ flags, int* __restrict__ release,
    float* __restrict__ out)
{
    const int tid = threadIdx.x;
    const int lane = tid & 63, wave = tid >> 6;
    const int mlane = lane & 15, quad = lane >> 4;
    const int jg = blockIdx.x;           // 128 blocks, one 16-col group each
    const int jcol = jg * 16 + mlane;
    const float bh = bhn[jcol];
    const unsigned short* __restrict__ Wr = Wht + (size_t)jcol * D;
    const unsigned short* __restrict__ Wz = Wht + (size_t)(D + jcol) * D;
    const unsigned short* __restrict__ Wn = Wht + (size_t)(2 * D + jcol) * D;
    const int maxlen = maxlen_p[0];

    for (int s = 0; s < maxlen; ++s) {
        const unsigned short* __restrict__ Hcur = (s & 1) ? Hh1 : Hh0;
        unsigned short* __restrict__ Hnxt = (s & 1) ? Hh0 : Hh1;
        const int active = n_active[s];
        const int mtiles = (active + 15) >> 4;

        for (int m0 = 0; m0 < mtiles; m0 += 32) {
            const int nmt = min(32, mtiles - m0);
            f32x4 aR[8], aZ[8], aN[8];
#pragma unroll
            for (int i = 0; i < 8; ++i) {
                aR[i] = (f32x4){0.f, 0.f, 0.f, 0.f};
                aZ[i] = (f32x4){0.f, 0.f, 0.f, 0.f};
                aN[i] = (f32x4){0.f, 0.f, 0.f, 0.f};
            }
            for (int kc = 0; kc < 64; ++kc) {
                const int koff = kc * 32 + quad * 8;
                bf16x8 br = *(const bf16x8*)&Wr[koff];
                bf16x8 bz = *(const bf16x8*)&Wz[koff];
                bf16x8 bn = *(const bf16x8*)&Wn[koff];
#pragma unroll
                for (int i = 0; i < 8; ++i) {
                    if (wave + 4 * i < nmt) {
                        bf16x8 a = *(const bf16x8*)&Hcur[
                            (size_t)((m0 + wave + 4 * i) * 16 + mlane) * D + koff];
                        aR[i] = __builtin_amdgcn_mfma_f32_16x16x32_bf16(a, br, aR[i], 0, 0, 0);
                        aZ[i] = __builtin_amdgcn_mfma_f32_16x16x32_bf16(a, bz, aZ[i], 0, 0, 0);
                        aN[i] = __builtin_amdgcn_mfma_f32_16x16x32_bf16(a, bn, aN[i], 0, 0, 0);
                    }
                }
            }
            // fused gate epilogue on C-frags (row = tile*16+quad*4+r, col = mlane)
#pragma unroll
            for (int i = 0; i < 8; ++i) {
                if (wave + 4 * i < nmt) {
                    int rb = (m0 + wave + 4 * i) * 16 + quad * 4;
#pragma unroll
                    for (int r = 0; r < 4; ++r) {
                        int p = rb + r;
                        if (p < active) {
                            int tt = st[p] + s;
                            size_t gbase = (size_t)tt * NG + jcol;
                            float gr = bf2f(gih[gbase]);
                            float gz = bf2f(gih[gbase + D]);
                            float gn = bf2f(gih[gbase + 2 * D]);
                            float ho = Hb[(size_t)p * D + jcol];
                            float rr = sigf(aR[i][r] + gr);
                            float zz = sigf(aZ[i][r] + gz);
                            float nn = tanhfast(gn + rr * (aN[i][r] + bh));
                            float h = (1.0f - zz) * nn + zz * ho;
                            Hb[(size_t)p * D + jcol] = h;
                            Hnxt[(size_t)p * D + jcol] = f2bf(h);
                            out[(size_t)tt * D + jcol] = h;
                            out[(size_t)(T + tt) * D + jcol] = h;
                        }
                    }
                }
            }
        }
        gbar(flags, release, s + 1);
    }
}

// ---------------------------------------------------------------------------
// Workspace layout (54.54 MB total):
//   [0,16K)  meta: st[1024] | n_active[1024] | nseg | maxlen | pad |
//            flags[128] @ int 2112 | release @ int 2304
//   +25.17M  Wbuf  bf16 [3][2048][2048]  (Wit, then OVERWRITTEN with Wht)
//   +12.58M  gih   bf16 [T][NG]
//   +8.39M   Hb    fp32 [T][D]
//   +4.19M   Hh0   bf16 [T][D]
//   +4.19M   Hh1   bf16 [T][D]   (head aliased as Xh; Xh dead after kA2)
// ---------------------------------------------------------------------------
extern "C" void kernel_launch(void* const* d_in, const int* in_sizes, int n_in,
                              void* d_out, int out_size, void* d_ws, size_t ws_size,
                              hipStream_t stream)
{
    const float* X    = (const float*)d_in[0];
    const int*   term = (const int*)  d_in[1];
    const float* last = (const float*)d_in[2];
    const float* wir  = (const float*)d_in[3];
    const float* wiz  = (const float*)d_in[4];
    const float* win  = (const float*)d_in[5];
    const float* bir  = (const float*)d_in[6];
    const float* biz  = (const float*)d_in[7];
    const float* bin  = (const float*)d_in[8];
    const float* whr  = (const float*)d_in[9];
    const float* whz  = (const float*)d_in[10];
    const float* whn  = (const float*)d_in[11];
    const float* bhn  = (const float*)d_in[12];
    float* out = (float*)d_out;

    char* ws = (char*)d_ws;
    int* meta = (int*)ws;
    int* st       = meta;
    int* n_active = meta + 1024;
    int* nseg_p   = meta + 2048;
    int* maxlen_p = meta + 2049;
    int* flags    = meta + 2112;
    int* release  = meta + 2304;
    size_t off = 16384;
    unsigned short* Wbuf = (unsigned short*)(ws + off); off += (size_t)3 * D * D * 2; // 25.17M
    unsigned short* gih  = (unsigned short*)(ws + off); off += (size_t)T * NG * 2;    // 12.58M
    float*          Hb   = (float*)(ws + off);          off += (size_t)T * D * 4;     // 8.39M
    unsigned short* Hh0  = (unsigned short*)(ws + off); off += (size_t)T * D * 2;     // 4.19M
    unsigned short* Hh1  = (unsigned short*)(ws + off);                                // 4.19M
    unsigned short* Xh   = Hh1;   // alias: Xh dead after kA2; Hh1 first written in kC

    kX<<<512, 256, 0, stream>>>(X, Xh);
    kB<<<1, 256, 0, stream>>>(term, st, n_active, nseg_p, maxlen_p);
    kB2<<<1024, 256, 0, stream>>>(last, term, st, nseg_p, Hb, Hh0);
    kW<<<dim3(32, 32, 3), 256, 0, stream>>>(wir, wiz, win, Wbuf);     // Wit
    kA2<<<dim3(48, 8), 256, 0, stream>>>(Xh, Wbuf, bir, biz, bin, gih);
    kW<<<dim3(32, 32, 3), 256, 0, stream>>>(whr, whz, whn, Wbuf);     // Wht (overwrite)

    const unsigned short* c_wht = Wbuf; const float* c_bhn = bhn;
    const unsigned short* c_gih = gih;
    float* c_hb = Hb; unsigned short* c_h0 = Hh0; unsigned short* c_h1 = Hh1;
    const int* c_st = st; const int* c_na = n_active; const int* c_ml = maxlen_p;
    int* c_fl = flags; int* c_rel = release; float* c_out = out;
    void* args[] = {&c_wht, &c_bhn, &c_gih, &c_hb, &c_h0, &c_h1,
                    &c_st, &c_na, &c_ml, &c_fl, &c_rel, &c_out};
    hipLaunchCooperativeKernel((void*)kC, dim3(KC_BLOCKS), dim3(256), args, 0, stream);
}